// Round 8
// baseline (1428.103 us; speedup 1.0000x reference)
//
#include <hip/hip_runtime.h>
#include <hip/hip_bf16.h>

#define B_ 4
#define C_ 80
#define T_ 800
#define R_ 3200   // B_*T_
#define DIN 160
#define NST 16
#define NC 16     // time chunks for parallel scan
#define LCH 50    // T_/NC

typedef const float* fp;

__device__ __forceinline__ void g2l16(const float* g, float* l) {
  __builtin_amdgcn_global_load_lds(
      (const __attribute__((address_space(1))) void*)g,
      (__attribute__((address_space(3))) void*)l,
      16, 0, 0);
}

__device__ __forceinline__ float blockSum(float v, float* sb) {
  for (int o = 32; o; o >>= 1) v += __shfl_xor(v, o);
  __syncthreads();
  if ((threadIdx.x & 63) == 0) sb[threadIdx.x >> 6] = v;
  __syncthreads();
  return sb[0] + sb[1] + sb[2] + sb[3];
}
__device__ __forceinline__ float blockMax(float v, float* sb) {
  for (int o = 32; o; o >>= 1) v = fmaxf(v, __shfl_xor(v, o));
  __syncthreads();
  if ((threadIdx.x & 63) == 0) sb[threadIdx.x >> 6] = v;
  __syncthreads();
  return fmaxf(fmaxf(sb[0], sb[1]), fmaxf(sb[2], sb[3]));
}

// ---- prep: W' = diag(g)W, u = colsum(W'), v = b@W (+bias), all 12 layers ----
__global__ __launch_bounds__(256) void prepw_k(fp in_proj, fp ff_w1,
    fp ln1_g, fp ln1_b, fp ln2_g, fp ln2_b, fp ff_b1,
    float* __restrict__ wp, float* __restrict__ uvb) {
  int idx = blockIdx.x * 256 + threadIdx.x;   // 0..7679
  int c = idx % 320, lm = idx / 320;
  int mat = lm & 1, l = lm >> 1;
  fp W = (mat ? ff_w1 : in_proj) + l * 25600;
  fp g = (mat ? ln2_g : ln1_g) + l * 80;
  fp b = (mat ? ln2_b : ln1_b) + l * 80;
  float* wpo = wp + lm * 25600;
  float u = 0.f, v = 0.f;
  for (int k = 0; k < 80; ++k) {
    float w = W[k * 320 + c];
    float gw = g[k] * w;
    wpo[k * 320 + c] = gw;
    u += gw;
    v += b[k] * w;
  }
  if (mat) v += ff_b1[l * 320 + c];
  uvb[lm * 640 + c] = u;
  uvb[lm * 640 + 320 + c] = v;
}

// ---- prep: transpose x_proj -> xpt[l][37][160] ------------------------------
__global__ __launch_bounds__(256) void prepx_k(fp x_proj, float* __restrict__ xpt) {
  int idx = blockIdx.x * 256 + threadIdx.x;   // 12*5920 = 71040
  if (idx >= 71040) return;
  int l = idx / 5920, r = idx % 5920;
  int c = r / 160, k = r % 160;
  xpt[idx] = x_proj[l * 5920 + k * 37 + c];
}

// ---- CMN + transpose: feat [B,C,T] -> x [B*T, C] ----------------------------
__global__ __launch_bounds__(256) void cmn_k(fp feat, float* __restrict__ x) {
  int bc = blockIdx.x;
  int b = bc / C_, c = bc % C_;
  const float* f = feat + (b * C_ + c) * T_;
  __shared__ float sb[4];
  int tid = threadIdx.x;
  float v[4]; float s = 0.f;
  #pragma unroll
  for (int i = 0; i < 4; ++i) {
    int t = tid + i * 256;
    v[i] = (t < T_) ? f[t] : 0.f;
    s += v[i];
  }
  s = blockSum(s, sb);
  float mu = s * (1.f / T_);
  #pragma unroll
  for (int i = 0; i < 4; ++i) {
    int t = tid + i * 256;
    if (t < T_) x[(b * T_ + t) * C_ + c] = v[i] - mu;
  }
}

// ---- row stats (mu, rs) for LN fold -----------------------------------------
__global__ __launch_bounds__(256) void rstat_k(const float* __restrict__ in,
                                               float* __restrict__ must) {
  int row = blockIdx.x * 16 + (threadIdx.x >> 4);
  int c16 = threadIdx.x & 15;
  float s = 0.f, q = 0.f;
  #pragma unroll
  for (int m = 0; m < 5; ++m) {
    float v = in[row * 80 + c16 + 16 * m];
    s += v; q += v * v;
  }
  s += __shfl_xor(s, 1); s += __shfl_xor(s, 2);
  s += __shfl_xor(s, 4); s += __shfl_xor(s, 8);
  q += __shfl_xor(q, 1); q += __shfl_xor(q, 2);
  q += __shfl_xor(q, 4); q += __shfl_xor(q, 8);
  if (c16 == 0) {
    float mu = s * 0.0125f;
    float rs = rsqrtf(fmaxf(q * 0.0125f - mu * mu, 0.f) + 1e-5f);
    must[row * 2] = mu;
    must[row * 2 + 1] = rs;
  }
}

// ---- per-wave GEMM, K=80, TN=64; LN folded via uv/must ----------------------
// EPI: 0 plain+LNfold, 1 LNfold+gelu, 3 att1 (pack in extra, no LN)
template<int EPI>
__global__ __launch_bounds__(256, 4) void gw_k(const float* __restrict__ A,
    fp W, fp uv, const float* __restrict__ must, const float* __restrict__ extra,
    float* __restrict__ out, int N) {
  __shared__ float SL[5120 + 4 * 1280];
  int tid = threadIdx.x, wv = tid >> 6, ln = tid & 63;
  int bid = blockIdx.x;
  int c0 = (bid / 50) * 64;
  int row0 = ((bid % 50) * 4 + wv) * 16;
  for (int ch = wv; ch < 20; ch += 4) {
    int m = ch * 256 + ln * 4;
    int kr = m >> 6, cc = m & 63;
    int lo = __builtin_amdgcn_readfirstlane(ch * 256);
    g2l16(W + kr * N + c0 + cc, SL + lo);
  }
  int abase = __builtin_amdgcn_readfirstlane(5120 + wv * 1280);
  float* As = SL + 5120 + wv * 1280;
  #pragma unroll
  for (int i = 0; i < 5; ++i) {
    int m = i * 256 + ln * 4;
    int r = m / 80, kk = m - r * 80;
    g2l16(A + (row0 + r) * 80 + kk, SL + abase + i * 256);
  }
  __syncthreads();
  int rq = ln >> 4, c16 = ln & 15;
  float acc[4][4] = {};
  #pragma unroll 2
  for (int k4 = 0; k4 < 80; k4 += 4) {
    float4 a[4], w[4];
    #pragma unroll
    for (int i = 0; i < 4; ++i)
      a[i] = *(const float4*)&As[(rq * 4 + i) * 80 + k4];
    #pragma unroll
    for (int kk = 0; kk < 4; ++kk)
      w[kk] = *(const float4*)&SL[(k4 + kk) * 64 + c16 * 4];
    #pragma unroll
    for (int i = 0; i < 4; ++i) {
      acc[i][0] += a[i].x*w[0].x + a[i].y*w[1].x + a[i].z*w[2].x + a[i].w*w[3].x;
      acc[i][1] += a[i].x*w[0].y + a[i].y*w[1].y + a[i].z*w[2].y + a[i].w*w[3].y;
      acc[i][2] += a[i].x*w[0].z + a[i].y*w[1].z + a[i].z*w[2].z + a[i].w*w[3].z;
      acc[i][3] += a[i].x*w[0].w + a[i].y*w[1].w + a[i].z*w[2].w + a[i].w*w[3].w;
    }
  }
  float ua[4], va[4];
  if (EPI != 3) {
    *(float4*)ua = *(const float4*)&uv[c0 + c16 * 4];
    *(float4*)va = *(const float4*)&uv[N + c0 + c16 * 4];
  }
  #pragma unroll
  for (int i = 0; i < 4; ++i) {
    int row = row0 + rq * 4 + i;
    float mu = 0.f, rs = 1.f;
    if (EPI != 3) {
      float2 ms = *(const float2*)&must[row * 2];
      mu = ms.x; rs = ms.y;
    }
    float4 o;
    float* op = &o.x;
    #pragma unroll
    for (int j = 0; j < 4; ++j) {
      float v = acc[i][j];
      if (EPI == 3) {
        int c = c0 + c16 * 4 + j;
        v += extra[(row / T_) * 128 + c];
        v = fmaxf(v, 0.f);
        v = v * extra[512 + c] + extra[640 + c];
        v = tanhf(v);
      } else {
        v = rs * v - mu * rs * ua[j] + va[j];
        if (EPI == 1) v = 0.5f * v * (1.f + erff(v * 0.70710678118f));
      }
      op[j] = v;
    }
    *(float4*)&out[row * N + c0 + c16 * 4] = o;
  }
}

// ---- block-coop GEMM, N=80 full width, 16-row tiles, transposed-W LDS -------
template<int EPI, int KCH, int NKC, int SUM2, int STAT>
__global__ __launch_bounds__(256, 4) void gc_k(const float* __restrict__ A,
    fp W, fp bias, const float* __restrict__ extra, float* __restrict__ out,
    int Astride, float* __restrict__ must) {
  constexpr int P = KCH + 4;
  __shared__ float As[16 * P];
  __shared__ float Wt[80 * P];
  int tid = threadIdx.x;
  int row0 = blockIdx.x * 16;
  int rr = tid >> 4, c16 = tid & 15;
  float acc[5] = {};
  for (int kc = 0; kc < NKC; ++kc) {
    if (kc) __syncthreads();
    #pragma unroll
    for (int i = 0; i < 16 * KCH / 256; ++i) {
      int e = tid + i * 256;
      int r = e / KCH, k = e - r * KCH;
      float v;
      if (SUM2) v = A[(row0 + r) * 320 + k] + A[(row0 + r) * 320 + 160 + k];
      else      v = A[(row0 + r) * Astride + kc * KCH + k];
      As[r * P + k] = v;
    }
    #pragma unroll
    for (int i = 0; i < KCH * 80 / 256; ++i) {
      int e = tid + i * 256;
      int kr = e / 80, c = e - kr * 80;
      Wt[c * P + kr] = W[(kc * KCH + kr) * 80 + c];
    }
    __syncthreads();
    #pragma unroll 4
    for (int k4 = 0; k4 < KCH; k4 += 4) {
      float4 a = *(const float4*)&As[rr * P + k4];
      #pragma unroll
      for (int m = 0; m < 5; ++m) {
        float4 w = *(const float4*)&Wt[(c16 + 16 * m) * P + k4];
        acc[m] += a.x * w.x + a.y * w.y + a.z * w.z + a.w * w.w;
      }
    }
  }
  int row = row0 + rr;
  float s = 0.f, q = 0.f;
  #pragma unroll
  for (int m = 0; m < 5; ++m) {
    int c = c16 + 16 * m;
    float v = acc[m];
    if (EPI == 2) v += bias[c] + extra[row * 80 + c];
    else if (EPI == 4) v += bias[c];
    out[row * 80 + c] = v;
    if (STAT) { s += v; q += v * v; }
  }
  if (STAT) {
    s += __shfl_xor(s, 1); s += __shfl_xor(s, 2);
    s += __shfl_xor(s, 4); s += __shfl_xor(s, 8);
    q += __shfl_xor(q, 1); q += __shfl_xor(q, 2);
    q += __shfl_xor(q, 4); q += __shfl_xor(q, 8);
    if (c16 == 0) {
      float mu = s * 0.0125f;
      float rs = rsqrtf(fmaxf(q * 0.0125f - mu * mu, 0.f) + 1e-5f);
      must[row * 2] = mu;
      must[row * 2 + 1] = rs;
    }
  }
}

// ---- fused conv(K=4,causal)+SiLU + x_proj + dt_proj+softplus ----------------
// xpt pre-transposed [37][160] per layer; LDS stage is a straight copy.
__global__ __launch_bounds__(256) void cx_k(const float* __restrict__ xz,
    fp cw, fp cb, fp xptl, fp dtw, fp dtb,
    float* __restrict__ xcf, float* __restrict__ xcbb,
    float* __restrict__ dbc2, float* __restrict__ dt2) {
  __shared__ float xcl[25 * 164];
  __shared__ float xpT[37 * 164];
  __shared__ float dbcl[25 * 40];
  int bi = blockIdx.x;
  int tc = bi & 31;
  int b = (bi >> 5) & 3;
  int dir = bi >> 7;
  int t0 = tc * 25;
  int tid = threadIdx.x;
  // coalesced stage of pre-transposed x_proj into padded LDS
  #pragma unroll 4
  for (int i = 0; i < 24; ++i) {
    int e = tid + i * 256;
    if (e < 5920) {
      int c = e / 160, k = e - c * 160;
      xpT[c * 164 + k] = xptl[e];
    }
  }
  float* xco = dir ? xcbb : xcf;
  #pragma unroll 4
  for (int i = 0; i < 16; ++i) {
    int e = tid + i * 256;
    if (e < 4000) {
      int ii = e / 160, d = e - ii * 160;
      int t = t0 + ii;
      float acc = cb[d];
      #pragma unroll
      for (int k = 0; k < 4; ++k) {
        int tt = t - 3 + k;
        if (tt >= 0) {
          int src = dir ? (T_ - 1 - tt) : tt;
          acc += cw[k * DIN + d] * xz[(b * T_ + src) * 320 + d];
        }
      }
      float v = acc / (1.f + __expf(-acc));
      xcl[ii * 164 + d] = v;
      xco[(b * T_ + t) * DIN + d] = v;
    }
  }
  __syncthreads();
  int g = tid >> 3, j = tid & 7;
  int grow0 = dir * R_ + b * T_ + t0;
  if (g < 25) {
    float accv[5] = {};
    for (int k4 = 0; k4 < 160; k4 += 4) {
      float4 a = *(const float4*)&xcl[g * 164 + k4];
      #pragma unroll
      for (int m = 0; m < 5; ++m) {
        int c = j + 8 * m;
        if (c < 37) {
          float4 w = *(const float4*)&xpT[c * 164 + k4];
          accv[m] += a.x * w.x + a.y * w.y + a.z * w.z + a.w * w.w;
        }
      }
    }
    #pragma unroll
    for (int m = 0; m < 5; ++m) {
      int c = j + 8 * m;
      if (c < 37) {
        dbcl[g * 40 + c] = accv[m];
        dbc2[(grow0 + g) * 37 + c] = accv[m];
      }
    }
  }
  __syncthreads();
  #pragma unroll 4
  for (int i = 0; i < 16; ++i) {
    int e = tid + i * 256;
    if (e < 4000) {
      int ii = e / 160, d = e - ii * 160;
      float v = dtb[d];
      #pragma unroll
      for (int m = 0; m < 5; ++m) v += dbcl[ii * 40 + m] * dtw[m * DIN + d];
      v = fmaxf(v, 0.f) + log1pf(expf(-fabsf(v)));
      dt2[(grow0 + ii) * DIN + d] = v;
    }
  }
}

// ---- chunked parallel scan, phase A -----------------------------------------
__global__ __launch_bounds__(256) void scanA_k(const float* __restrict__ dt2,
    const float* __restrict__ xcf, const float* __restrict__ xcbb,
    const float* __restrict__ dbc2, fp A_log,
    float* __restrict__ hend, float* __restrict__ pprod) {
  int bi = blockIdx.x;
  int cch = bi % NC; int rem = bi / NC;
  int dblk = rem % 10; rem /= 10;
  int b = rem % 4; int dir = rem / 4;
  int d0 = dblk * 16;
  int tid = threadIdx.x, dl = tid >> 4, n = tid & 15;
  int d = d0 + dl;
  float Areg = -__expf(A_log[d * NST + n]);
  __shared__ float sdt[LCH][16], sdx[LCH][16], sB[LCH][16];
  const float* xc = dir ? xcbb : xcf;
  int rbase = dir * R_ + b * T_ + cch * LCH;
  int rloc0 = b * T_ + cch * LCH;
  for (int e = tid; e < LCH * 16; e += 256) {
    int i = e >> 4, jj = e & 15;
    int grow = rbase + i;
    float dtv = dt2[grow * DIN + d0 + jj];
    sdt[i][jj] = dtv;
    sdx[i][jj] = dtv * xc[(rloc0 + i) * DIN + d0 + jj];
    sB[i][jj]  = dbc2[grow * 37 + 5 + jj];
  }
  __syncthreads();
  float h = 0.f, Pp = 1.f;
  #pragma unroll 2
  for (int i = 0; i < LCH; ++i) {
    float a = __expf(sdt[i][dl] * Areg);
    h = a * h + sdx[i][dl] * sB[i][n];
    Pp *= a;
  }
  hend[bi * 256 + tid] = h;
  pprod[bi * 256 + tid] = Pp;
}

// ---- phase C: prefix (scanB fused) + recompute chunk + gated write ----------
__global__ __launch_bounds__(256) void scanC_k(const float* __restrict__ dt2,
    const float* __restrict__ dbc2, const float* __restrict__ xcf,
    const float* __restrict__ xcbb, const float* __restrict__ xz,
    fp A_log, fp Dp, const float* __restrict__ hend,
    const float* __restrict__ pprod, float* __restrict__ ygcat) {
  int bi = blockIdx.x;
  int cch = bi % NC; int rem = bi / NC;
  int dblk = rem % 10; rem /= 10;
  int b = rem % 4; int dir = rem / 4;
  int d0 = dblk * 16;
  int tid = threadIdx.x, dl = tid >> 4, n = tid & 15;
  int d = d0 + dl;
  float Areg = -__expf(A_log[d * NST + n]);
  __shared__ float sdt[LCH][16], sdx[LCH][16], sB[LCH][16], sC[LCH][16];
  __shared__ float sY[LCH][16];
  const float* xc = dir ? xcbb : xcf;
  int rbase = dir * R_ + b * T_ + cch * LCH;
  int rloc0 = b * T_ + cch * LCH;
  int sbase = (bi / NC) * (NC * 256) + tid;
  float h = 0.f;
  #pragma unroll
  for (int cc = 0; cc < NC; ++cc) {
    float p = pprod[sbase + cc * 256];
    float e = hend[sbase + cc * 256];
    if (cc < cch) h = p * h + e;
  }
  for (int e = tid; e < LCH * 16; e += 256) {
    int i = e >> 4, jj = e & 15;
    int grow = rbase + i;
    float dtv = dt2[grow * DIN + d0 + jj];
    sdt[i][jj] = dtv;
    sdx[i][jj] = dtv * xc[(rloc0 + i) * DIN + d0 + jj];
    sB[i][jj]  = dbc2[grow * 37 + 5 + jj];
    sC[i][jj]  = dbc2[grow * 37 + 21 + jj];
  }
  __syncthreads();
  for (int i = 0; i < LCH; ++i) {
    float a = __expf(sdt[i][dl] * Areg);
    h = a * h + sdx[i][dl] * sB[i][n];
    float y = h * sC[i][n];
    y += __shfl_xor(y, 1);
    y += __shfl_xor(y, 2);
    y += __shfl_xor(y, 4);
    y += __shfl_xor(y, 8);
    if (n == 0) sY[i][dl] = y;
  }
  __syncthreads();
  for (int e = tid; e < LCH * 16; e += 256) {
    int i = e >> 4, jj = e & 15;
    int t = cch * LCH + i;
    int rloc = b * T_ + t;
    float xcv = xc[rloc * DIN + d0 + jj];
    int orow = dir ? (b * T_ + (T_ - 1 - t)) : rloc;
    float z = xz[orow * 320 + 160 + d0 + jj];
    float sg = 1.f / (1.f + __expf(-z));
    ygcat[orow * 320 + dir * 160 + d0 + jj] = (sY[i][jj] + xcv * Dp[d0 + jj]) * (z * sg);
  }
}

// ---- pooling: per-(b,c) mean/std over T -------------------------------------
__global__ __launch_bounds__(256) void stats_k(const float* __restrict__ x,
                                               float* __restrict__ meanv, float* __restrict__ stdv) {
  int bc = blockIdx.x; int b = bc / C_, c = bc % C_;
  __shared__ float sb[4];
  int tid = threadIdx.x;
  float v[4]; float s = 0.f;
  #pragma unroll
  for (int i = 0; i < 4; ++i) {
    int t = tid + i * 256;
    v[i] = (t < T_) ? x[(b * T_ + t) * C_ + c] : 0.f;
    s += v[i];
  }
  s = blockSum(s, sb);
  float mu = s * (1.f / T_);
  float q = 0.f;
  #pragma unroll
  for (int i = 0; i < 4; ++i) {
    int t = tid + i * 256;
    if (t < T_) { float dd = v[i] - mu; q += dd * dd; }
  }
  q = blockSum(q, sb);
  if (tid == 0) { meanv[bc] = mu; stdv[bc] = sqrtf(fmaxf(q * (1.f / T_), 1e-12f)); }
}

// ---- att1 pack --------------------------------------------------------------
__global__ __launch_bounds__(256) void prep_k(const float* __restrict__ meanv,
    const float* __restrict__ stdv, fp w1, fp ab1, fp g1p, fp b1p, fp m1p, fp v1p,
    float* __restrict__ pack) {
  int idx = blockIdx.x * 256 + threadIdx.x;
  if (idx < 512) {
    int b = idx / 128, dcol = idx % 128;
    float acc = ab1[dcol];
    for (int c = 0; c < C_; ++c) {
      acc += meanv[b * C_ + c] * w1[(C_ + c) * 128 + dcol];
      acc += stdv[b * C_ + c] * w1[(2 * C_ + c) * 128 + dcol];
    }
    pack[idx] = acc;
  } else if (idx < 640) {
    int dcol = idx - 512;
    float kv = g1p[dcol] * rsqrtf(v1p[dcol] + 1e-5f);
    pack[512 + dcol] = kv;
    pack[640 + dcol] = b1p[dcol] - m1p[dcol] * kv;
  }
}

// ---- softmax over T + weighted stats + bn2 ----------------------------------
__global__ __launch_bounds__(256) void pool_k(const float* __restrict__ x,
    const float* __restrict__ scores, fp g2, fp b2, fp m2, fp v2,
    float* __restrict__ pooledn) {
  int bc = blockIdx.x; int b = bc / C_, c = bc % C_;
  __shared__ float sb[4];
  int tid = threadIdx.x;
  float sv[4], xv[4];
  float mx = -1e30f;
  #pragma unroll
  for (int i = 0; i < 4; ++i) {
    int t = tid + i * 256;
    if (t < T_) { sv[i] = scores[(b * T_ + t) * C_ + c]; xv[i] = x[(b * T_ + t) * C_ + c]; }
    else { sv[i] = -1e30f; xv[i] = 0.f; }
    mx = fmaxf(mx, sv[i]);
  }
  mx = blockMax(mx, sb);
  float se = 0.f, sx = 0.f, sxx = 0.f;
  #pragma unroll
  for (int i = 0; i < 4; ++i) {
    float e = expf(sv[i] - mx);
    se += e; sx += e * xv[i]; sxx += e * xv[i] * xv[i];
  }
  se = blockSum(se, sb);
  sx = blockSum(sx, sb);
  sxx = blockSum(sxx, sb);
  if (tid == 0) {
    float mu = sx / se;
    float sg = sqrtf(fmaxf(sxx / se - mu * mu, 1e-12f));
    int j0 = c, j1 = C_ + c;
    pooledn[b * 160 + j0] = (mu - m2[j0]) * rsqrtf(v2[j0] + 1e-5f) * g2[j0] + b2[j0];
    pooledn[b * 160 + j1] = (sg - m2[j1]) * rsqrtf(v2[j1] + 1e-5f) * g2[j1] + b2[j1];
  }
}

// ---- final fc ---------------------------------------------------------------
__global__ __launch_bounds__(256) void fc_k(const float* __restrict__ pooledn, fp fw, fp fb,
                                            float* __restrict__ out) {
  int idx = blockIdx.x * 256 + threadIdx.x;
  if (idx >= 4 * 192) return;
  int b = idx / 192, e = idx % 192;
  float acc = fb[e];
  for (int i = 0; i < 160; ++i) acc += pooledn[b * 160 + i] * fw[i * 192 + e];
  out[idx] = acc;
}

extern "C" void kernel_launch(void* const* d_in, const int* in_sizes, int n_in,
                              void* d_out, int out_size, void* d_ws, size_t ws_size,
                              hipStream_t stream) {
  fp feat   = (fp)d_in[0];
  fp ln1_g  = (fp)d_in[1];  fp ln1_b  = (fp)d_in[2];
  fp in_proj= (fp)d_in[3];
  fp conv_w = (fp)d_in[4];  fp conv_b = (fp)d_in[5];
  fp x_proj = (fp)d_in[6];
  fp dt_w   = (fp)d_in[7];  fp dt_b   = (fp)d_in[8];
  fp A_log  = (fp)d_in[9];  fp Dp     = (fp)d_in[10];
  fp out_proj=(fp)d_in[11];
  fp ln2_g  = (fp)d_in[12]; fp ln2_b  = (fp)d_in[13];
  fp ff_w1  = (fp)d_in[14]; fp ff_b1  = (fp)d_in[15];
  fp ff_w2  = (fp)d_in[16]; fp ff_b2  = (fp)d_in[17];
  fp att_w1 = (fp)d_in[18]; fp att_b1 = (fp)d_in[19];
  fp bn1_g  = (fp)d_in[20]; fp bn1_b  = (fp)d_in[21];
  fp bn1_m  = (fp)d_in[22]; fp bn1_v  = (fp)d_in[23];
  fp att_w2 = (fp)d_in[24]; fp att_b2 = (fp)d_in[25];
  fp bn2_g  = (fp)d_in[26]; fp bn2_b  = (fp)d_in[27];
  fp bn2_m  = (fp)d_in[28]; fp bn2_v  = (fp)d_in[29];
  fp fc_w   = (fp)d_in[30]; fp fc_b   = (fp)d_in[31];

  float* ws   = (float*)d_ws;
  float* x    = ws;               // 256000
  float* xz   = ws + 256000;      // 1024000
  float* xcf  = ws + 1280000;     // 512000
  float* xcb  = ws + 1792000;     // 512000
  float* dbc2 = ws + 2304000;     // 236800
  float* dt2  = ws + 2540800;     // 1024000
  float* hend = ws + 3564800;     // 327680
  float* pprod= ws + 3892480;     // 327680
  float* ygcat= ws + 4220160;     // 1024000
  float* sbuf = ws + 5244160;     // 256000
  float* meanv= ws + 5500160;     // 320
  float* stdv = ws + 5500480;     // 320
  float* pack = ws + 5500800;     // 768
  float* pooledn = ws + 5501568;  // 640
  float* wp   = ws + 5502208;     // 614400 (12*2*25600)
  float* uvb  = ws + 6116608;     // 15360  (12*2*640)
  float* mst_x= ws + 6131968;     // 6400
  float* mst_s= ws + 6138368;     // 6400
  float* xpt  = ws + 6144768;     // 71040 (end 6215808 = 24.9 MiB)
  float* g1   = xz;               // alias: xz free after scanC
  float* a1b  = hend;             // alias: pooling only
  float* sc   = dt2;              // alias: pooling only

  prepw_k<<<30, 256, 0, stream>>>(in_proj, ff_w1, ln1_g, ln1_b, ln2_g, ln2_b,
                                  ff_b1, wp, uvb);
  prepx_k<<<278, 256, 0, stream>>>(x_proj, xpt);
  cmn_k<<<320, 256, 0, stream>>>(feat, x);
  rstat_k<<<200, 256, 0, stream>>>(x, mst_x);

  for (int l = 0; l < 12; ++l) {
    gw_k<0><<<250, 256, 0, stream>>>(x, wp + (2 * l) * 25600, uvb + (2 * l) * 640,
                                     mst_x, nullptr, xz, 320);
    cx_k<<<256, 256, 0, stream>>>(xz, conv_w + l * 640, conv_b + l * 160,
                                  xpt + l * 5920, dt_w + l * 800, dt_b + l * 160,
                                  xcf, xcb, dbc2, dt2);
    scanA_k<<<1280, 256, 0, stream>>>(dt2, xcf, xcb, dbc2, A_log + l * 2560, hend, pprod);
    scanC_k<<<1280, 256, 0, stream>>>(dt2, dbc2, xcf, xcb, xz, A_log + l * 2560,
                                      Dp + l * 160, hend, pprod, ygcat);
    gc_k<0, 160, 1, 1, 1><<<200, 256, 0, stream>>>(ygcat, out_proj + l * 12800,
                                                   nullptr, nullptr, sbuf, 320, mst_s);
    gw_k<1><<<250, 256, 0, stream>>>(sbuf, wp + (2 * l + 1) * 25600,
                                     uvb + (2 * l + 1) * 640, mst_s, nullptr, g1, 320);
    gc_k<2, 160, 2, 0, 1><<<200, 256, 0, stream>>>(g1, ff_w2 + l * 25600,
                                                   ff_b2 + l * 80, x, x, 320, mst_x);
  }

  stats_k<<<320, 256, 0, stream>>>(x, meanv, stdv);
  prep_k<<<3, 256, 0, stream>>>(meanv, stdv, att_w1, att_b1, bn1_g, bn1_b, bn1_m, bn1_v, pack);
  gw_k<3><<<100, 256, 0, stream>>>(x, att_w1, nullptr, nullptr, pack, a1b, 128);
  gc_k<4, 128, 1, 0, 0><<<200, 256, 0, stream>>>(a1b, att_w2, att_b2, nullptr, sc, 128, nullptr);
  pool_k<<<320, 256, 0, stream>>>(x, sc, bn2_g, bn2_b, bn2_m, bn2_v, pooledn);
  fc_k<<<3, 256, 0, stream>>>(pooledn, fc_w, fc_b, (float*)d_out);
}

// Round 9
// 1376.748 us; speedup vs baseline: 1.0373x; 1.0373x over previous
//
#include <hip/hip_runtime.h>
#include <hip/hip_bf16.h>

#define B_ 4
#define C_ 80
#define T_ 800
#define R_ 3200   // B_*T_
#define DIN 160
#define NST 16
#define NC 16     // time chunks for parallel scan
#define LCH 50    // T_/NC

typedef const float* fp;

__device__ __forceinline__ void g2l16(const float* g, float* l) {
  __builtin_amdgcn_global_load_lds(
      (const __attribute__((address_space(1))) void*)g,
      (__attribute__((address_space(3))) void*)l,
      16, 0, 0);
}

__device__ __forceinline__ float blockSum(float v, float* sb) {
  for (int o = 32; o; o >>= 1) v += __shfl_xor(v, o);
  __syncthreads();
  if ((threadIdx.x & 63) == 0) sb[threadIdx.x >> 6] = v;
  __syncthreads();
  return sb[0] + sb[1] + sb[2] + sb[3];
}
__device__ __forceinline__ float blockMax(float v, float* sb) {
  for (int o = 32; o; o >>= 1) v = fmaxf(v, __shfl_xor(v, o));
  __syncthreads();
  if ((threadIdx.x & 63) == 0) sb[threadIdx.x >> 6] = v;
  __syncthreads();
  return fmaxf(fmaxf(sb[0], sb[1]), fmaxf(sb[2], sb[3]));
}

// ---- prep: W' = diag(g)W, u = colsum(W'), v = b@W (+bias), all 12 layers ----
__global__ __launch_bounds__(256) void prepw_k(fp in_proj, fp ff_w1,
    fp ln1_g, fp ln1_b, fp ln2_g, fp ln2_b, fp ff_b1,
    float* __restrict__ wp, float* __restrict__ uvb) {
  int idx = blockIdx.x * 256 + threadIdx.x;   // 0..7679
  int c = idx % 320, lm = idx / 320;
  int mat = lm & 1, l = lm >> 1;
  fp W = (mat ? ff_w1 : in_proj) + l * 25600;
  fp g = (mat ? ln2_g : ln1_g) + l * 80;
  fp b = (mat ? ln2_b : ln1_b) + l * 80;
  float* wpo = wp + lm * 25600;
  float u = 0.f, v = 0.f;
  for (int k = 0; k < 80; ++k) {
    float w = W[k * 320 + c];
    float gw = g[k] * w;
    wpo[k * 320 + c] = gw;
    u += gw;
    v += b[k] * w;
  }
  if (mat) v += ff_b1[l * 320 + c];
  uvb[lm * 640 + c] = u;
  uvb[lm * 640 + 320 + c] = v;
}

// ---- prep: transpose x_proj -> xpt[l][37][160] ------------------------------
__global__ __launch_bounds__(256) void prepx_k(fp x_proj, float* __restrict__ xpt) {
  int idx = blockIdx.x * 256 + threadIdx.x;   // 12*5920 = 71040
  if (idx >= 71040) return;
  int l = idx / 5920, r = idx % 5920;
  int c = r / 160, k = r % 160;
  xpt[idx] = x_proj[l * 5920 + k * 37 + c];
}

// ---- CMN + transpose: feat [B,C,T] -> x [B*T, C] ----------------------------
__global__ __launch_bounds__(256) void cmn_k(fp feat, float* __restrict__ x) {
  int bc = blockIdx.x;
  int b = bc / C_, c = bc % C_;
  const float* f = feat + (b * C_ + c) * T_;
  __shared__ float sb[4];
  int tid = threadIdx.x;
  float v[4]; float s = 0.f;
  #pragma unroll
  for (int i = 0; i < 4; ++i) {
    int t = tid + i * 256;
    v[i] = (t < T_) ? f[t] : 0.f;
    s += v[i];
  }
  s = blockSum(s, sb);
  float mu = s * (1.f / T_);
  #pragma unroll
  for (int i = 0; i < 4; ++i) {
    int t = tid + i * 256;
    if (t < T_) x[(b * T_ + t) * C_ + c] = v[i] - mu;
  }
}

// ---- row stats (mu, rs) for LN fold -----------------------------------------
__global__ __launch_bounds__(256) void rstat_k(const float* __restrict__ in,
                                               float* __restrict__ must) {
  int row = blockIdx.x * 16 + (threadIdx.x >> 4);
  int c16 = threadIdx.x & 15;
  float s = 0.f, q = 0.f;
  #pragma unroll
  for (int m = 0; m < 5; ++m) {
    float v = in[row * 80 + c16 + 16 * m];
    s += v; q += v * v;
  }
  s += __shfl_xor(s, 1); s += __shfl_xor(s, 2);
  s += __shfl_xor(s, 4); s += __shfl_xor(s, 8);
  q += __shfl_xor(q, 1); q += __shfl_xor(q, 2);
  q += __shfl_xor(q, 4); q += __shfl_xor(q, 8);
  if (c16 == 0) {
    float mu = s * 0.0125f;
    float rs = rsqrtf(fmaxf(q * 0.0125f - mu * mu, 0.f) + 1e-5f);
    must[row * 2] = mu;
    must[row * 2 + 1] = rs;
  }
}

// ---- per-wave GEMM, K=80, TN=64; LN folded via uv/must ----------------------
// EPI: 0 plain+LNfold, 1 LNfold+gelu, 3 att1 (pack in extra, no LN)
template<int EPI>
__global__ __launch_bounds__(256, 4) void gw_k(const float* __restrict__ A,
    fp W, fp uv, const float* __restrict__ must, const float* __restrict__ extra,
    float* __restrict__ out, int N) {
  __shared__ float SL[5120 + 4 * 1280];
  int tid = threadIdx.x, wv = tid >> 6, ln = tid & 63;
  int bid = blockIdx.x;
  int c0 = (bid / 50) * 64;
  int row0 = ((bid % 50) * 4 + wv) * 16;
  for (int ch = wv; ch < 20; ch += 4) {
    int m = ch * 256 + ln * 4;
    int kr = m >> 6, cc = m & 63;
    int lo = __builtin_amdgcn_readfirstlane(ch * 256);
    g2l16(W + kr * N + c0 + cc, SL + lo);
  }
  int abase = __builtin_amdgcn_readfirstlane(5120 + wv * 1280);
  float* As = SL + 5120 + wv * 1280;
  #pragma unroll
  for (int i = 0; i < 5; ++i) {
    int m = i * 256 + ln * 4;
    int r = m / 80, kk = m - r * 80;
    g2l16(A + (row0 + r) * 80 + kk, SL + abase + i * 256);
  }
  __syncthreads();
  int rq = ln >> 4, c16 = ln & 15;
  float acc[4][4] = {};
  #pragma unroll 2
  for (int k4 = 0; k4 < 80; k4 += 4) {
    float4 a[4], w[4];
    #pragma unroll
    for (int i = 0; i < 4; ++i)
      a[i] = *(const float4*)&As[(rq * 4 + i) * 80 + k4];
    #pragma unroll
    for (int kk = 0; kk < 4; ++kk)
      w[kk] = *(const float4*)&SL[(k4 + kk) * 64 + c16 * 4];
    #pragma unroll
    for (int i = 0; i < 4; ++i) {
      acc[i][0] += a[i].x*w[0].x + a[i].y*w[1].x + a[i].z*w[2].x + a[i].w*w[3].x;
      acc[i][1] += a[i].x*w[0].y + a[i].y*w[1].y + a[i].z*w[2].y + a[i].w*w[3].y;
      acc[i][2] += a[i].x*w[0].z + a[i].y*w[1].z + a[i].z*w[2].z + a[i].w*w[3].z;
      acc[i][3] += a[i].x*w[0].w + a[i].y*w[1].w + a[i].z*w[2].w + a[i].w*w[3].w;
    }
  }
  float ua[4], va[4];
  if (EPI != 3) {
    *(float4*)ua = *(const float4*)&uv[c0 + c16 * 4];
    *(float4*)va = *(const float4*)&uv[N + c0 + c16 * 4];
  }
  #pragma unroll
  for (int i = 0; i < 4; ++i) {
    int row = row0 + rq * 4 + i;
    float mu = 0.f, rs = 1.f;
    if (EPI != 3) {
      float2 ms = *(const float2*)&must[row * 2];
      mu = ms.x; rs = ms.y;
    }
    float4 o;
    float* op = &o.x;
    #pragma unroll
    for (int j = 0; j < 4; ++j) {
      float v = acc[i][j];
      if (EPI == 3) {
        int c = c0 + c16 * 4 + j;
        v += extra[(row / T_) * 128 + c];
        v = fmaxf(v, 0.f);
        v = v * extra[512 + c] + extra[640 + c];
        v = tanhf(v);
      } else {
        v = rs * v - mu * rs * ua[j] + va[j];
        if (EPI == 1) v = 0.5f * v * (1.f + erff(v * 0.70710678118f));
      }
      op[j] = v;
    }
    *(float4*)&out[row * N + c0 + c16 * 4] = o;
  }
}

// ---- block-coop GEMM, N=80 full width, 16-row tiles, transposed-W LDS -------
template<int EPI, int KCH, int NKC, int SUM2, int STAT>
__global__ __launch_bounds__(256, 4) void gc_k(const float* __restrict__ A,
    fp W, fp bias, const float* __restrict__ extra, float* __restrict__ out,
    int Astride, float* __restrict__ must) {
  constexpr int P = KCH + 4;
  __shared__ float As[16 * P];
  __shared__ float Wt[80 * P];
  int tid = threadIdx.x;
  int row0 = blockIdx.x * 16;
  int rr = tid >> 4, c16 = tid & 15;
  float acc[5] = {};
  for (int kc = 0; kc < NKC; ++kc) {
    if (kc) __syncthreads();
    #pragma unroll
    for (int i = 0; i < 16 * KCH / 256; ++i) {
      int e = tid + i * 256;
      int r = e / KCH, k = e - r * KCH;
      float v;
      if (SUM2) v = A[(row0 + r) * 320 + k] + A[(row0 + r) * 320 + 160 + k];
      else      v = A[(row0 + r) * Astride + kc * KCH + k];
      As[r * P + k] = v;
    }
    #pragma unroll
    for (int i = 0; i < KCH * 80 / 256; ++i) {
      int e = tid + i * 256;
      int kr = e / 80, c = e - kr * 80;
      Wt[c * P + kr] = W[(kc * KCH + kr) * 80 + c];
    }
    __syncthreads();
    #pragma unroll 4
    for (int k4 = 0; k4 < KCH; k4 += 4) {
      float4 a = *(const float4*)&As[rr * P + k4];
      #pragma unroll
      for (int m = 0; m < 5; ++m) {
        float4 w = *(const float4*)&Wt[(c16 + 16 * m) * P + k4];
        acc[m] += a.x * w.x + a.y * w.y + a.z * w.z + a.w * w.w;
      }
    }
  }
  int row = row0 + rr;
  float s = 0.f, q = 0.f;
  #pragma unroll
  for (int m = 0; m < 5; ++m) {
    int c = c16 + 16 * m;
    float v = acc[m];
    if (EPI == 2) v += bias[c] + extra[row * 80 + c];
    else if (EPI == 4) v += bias[c];
    out[row * 80 + c] = v;
    if (STAT) { s += v; q += v * v; }
  }
  if (STAT) {
    s += __shfl_xor(s, 1); s += __shfl_xor(s, 2);
    s += __shfl_xor(s, 4); s += __shfl_xor(s, 8);
    q += __shfl_xor(q, 1); q += __shfl_xor(q, 2);
    q += __shfl_xor(q, 4); q += __shfl_xor(q, 8);
    if (c16 == 0) {
      float mu = s * 0.0125f;
      float rs = rsqrtf(fmaxf(q * 0.0125f - mu * mu, 0.f) + 1e-5f);
      must[row * 2] = mu;
      must[row * 2 + 1] = rs;
    }
  }
}

// ---- fused conv(K=4,causal)+SiLU + x_proj + dt_proj+softplus, 16-row chunks -
// grid 400 = (dir*4+b)*50 + tc; xpt streamed from global (L1-resident)
__global__ __launch_bounds__(256) void cxf_k(const float* __restrict__ xz,
    fp cw, fp cb, fp xptl, fp dtw, fp dtb,
    float* __restrict__ xcf, float* __restrict__ xcbb,
    float* __restrict__ dbc2, float* __restrict__ dt2) {
  __shared__ float As[16 * 164];
  __shared__ float dbcl[16 * 40];
  int bi = blockIdx.x;
  int tc = bi % 50; int rem = bi / 50;
  int b = rem & 3, dir = rem >> 2;
  int t0 = tc * 16;
  int tid = threadIdx.x;
  float* xco = dir ? xcbb : xcf;
  // phase 1: conv + SiLU into LDS + global
  #pragma unroll
  for (int i = 0; i < 3; ++i) {
    int e = tid + i * 256;
    if (e < 640) {
      int ii = e / 40, d4 = (e - ii * 40) * 4;
      int t = t0 + ii;
      float4 acc = *(const float4*)&cb[d4];
      #pragma unroll
      for (int k = 0; k < 4; ++k) {
        int tt = t - 3 + k;
        if (tt >= 0) {
          int src = dir ? (T_ - 1 - tt) : tt;
          float4 xv = *(const float4*)&xz[(b * T_ + src) * 320 + d4];
          float4 wv = *(const float4*)&cw[k * DIN + d4];
          acc.x += wv.x * xv.x; acc.y += wv.y * xv.y;
          acc.z += wv.z * xv.z; acc.w += wv.w * xv.w;
        }
      }
      float4 o;
      o.x = acc.x / (1.f + __expf(-acc.x));
      o.y = acc.y / (1.f + __expf(-acc.y));
      o.z = acc.z / (1.f + __expf(-acc.z));
      o.w = acc.w / (1.f + __expf(-acc.w));
      *(float4*)&As[ii * 164 + d4] = o;
      *(float4*)&xco[(b * T_ + t) * DIN + d4] = o;
    }
  }
  __syncthreads();
  // phase 2: dbc[16][37] = As @ xpt^T, all 256 threads
  int rr = tid >> 4, c16 = tid & 15;
  int grow0 = dir * R_ + b * T_ + t0;
  {
    float a0 = 0.f, a1 = 0.f, a2 = 0.f;
    for (int k4 = 0; k4 < 160; k4 += 4) {
      float4 a = *(const float4*)&As[rr * 164 + k4];
      float4 w0 = *(const float4*)&xptl[c16 * 160 + k4];
      float4 w1 = *(const float4*)&xptl[(c16 + 16) * 160 + k4];
      a0 += a.x * w0.x + a.y * w0.y + a.z * w0.z + a.w * w0.w;
      a1 += a.x * w1.x + a.y * w1.y + a.z * w1.z + a.w * w1.w;
      if (c16 < 5) {
        float4 w2 = *(const float4*)&xptl[(c16 + 32) * 160 + k4];
        a2 += a.x * w2.x + a.y * w2.y + a.z * w2.z + a.w * w2.w;
      }
    }
    dbcl[rr * 40 + c16] = a0;
    dbcl[rr * 40 + c16 + 16] = a1;
    dbc2[(grow0 + rr) * 37 + c16] = a0;
    dbc2[(grow0 + rr) * 37 + c16 + 16] = a1;
    if (c16 < 5) {
      dbcl[rr * 40 + c16 + 32] = a2;
      dbc2[(grow0 + rr) * 37 + c16 + 32] = a2;
    }
  }
  __syncthreads();
  // phase 3: dt = softplus(dbc[:,0:5] @ dt_w + dt_b)
  #pragma unroll
  for (int i = 0; i < 10; ++i) {
    int e = tid + i * 256;
    int ii = e / 160, d = e - ii * 160;
    float v = dtb[d];
    #pragma unroll
    for (int m = 0; m < 5; ++m) v += dbcl[ii * 40 + m] * dtw[m * DIN + d];
    v = fmaxf(v, 0.f) + log1pf(expf(-fabsf(v)));
    dt2[(grow0 + ii) * DIN + d] = v;
  }
}

// ---- chunked parallel scan, phase A -----------------------------------------
__global__ __launch_bounds__(256) void scanA_k(const float* __restrict__ dt2,
    const float* __restrict__ xcf, const float* __restrict__ xcbb,
    const float* __restrict__ dbc2, fp A_log,
    float* __restrict__ hend, float* __restrict__ pprod) {
  int bi = blockIdx.x;
  int cch = bi % NC; int rem = bi / NC;
  int dblk = rem % 10; rem /= 10;
  int b = rem % 4; int dir = rem / 4;
  int d0 = dblk * 16;
  int tid = threadIdx.x, dl = tid >> 4, n = tid & 15;
  int d = d0 + dl;
  float Areg = -__expf(A_log[d * NST + n]);
  __shared__ float sdt[LCH][16], sdx[LCH][16], sB[LCH][16];
  const float* xc = dir ? xcbb : xcf;
  int rbase = dir * R_ + b * T_ + cch * LCH;
  int rloc0 = b * T_ + cch * LCH;
  for (int e = tid; e < LCH * 16; e += 256) {
    int i = e >> 4, jj = e & 15;
    int grow = rbase + i;
    float dtv = dt2[grow * DIN + d0 + jj];
    sdt[i][jj] = dtv;
    sdx[i][jj] = dtv * xc[(rloc0 + i) * DIN + d0 + jj];
    sB[i][jj]  = dbc2[grow * 37 + 5 + jj];
  }
  __syncthreads();
  float h = 0.f, dts = 0.f;
  #pragma unroll 2
  for (int i = 0; i < LCH; ++i) {
    float dtv = sdt[i][dl];
    float a = __expf(dtv * Areg);
    h = a * h + sdx[i][dl] * sB[i][n];
    dts += dtv;
  }
  hend[bi * 256 + tid] = h;
  pprod[bi * 256 + tid] = __expf(dts * Areg);
}

// ---- phase C: prefix (scanB fused) + recompute chunk + gated write ----------
__global__ __launch_bounds__(256) void scanC_k(const float* __restrict__ dt2,
    const float* __restrict__ dbc2, const float* __restrict__ xcf,
    const float* __restrict__ xcbb, const float* __restrict__ xz,
    fp A_log, fp Dp, const float* __restrict__ hend,
    const float* __restrict__ pprod, float* __restrict__ ygcat) {
  int bi = blockIdx.x;
  int cch = bi % NC; int rem = bi / NC;
  int dblk = rem % 10; rem /= 10;
  int b = rem % 4; int dir = rem / 4;
  int d0 = dblk * 16;
  int tid = threadIdx.x, dl = tid >> 4, n = tid & 15;
  int d = d0 + dl;
  float Areg = -__expf(A_log[d * NST + n]);
  __shared__ float sdt[LCH][16], sdx[LCH][16], sB[LCH][16], sC[LCH][16];
  __shared__ float sY[LCH][16];
  const float* xc = dir ? xcbb : xcf;
  int rbase = dir * R_ + b * T_ + cch * LCH;
  int rloc0 = b * T_ + cch * LCH;
  int sbase = (bi / NC) * (NC * 256) + tid;
  float h = 0.f;
  #pragma unroll
  for (int cc = 0; cc < NC; ++cc) {
    float p = pprod[sbase + cc * 256];
    float e = hend[sbase + cc * 256];
    if (cc < cch) h = p * h + e;
  }
  for (int e = tid; e < LCH * 16; e += 256) {
    int i = e >> 4, jj = e & 15;
    int grow = rbase + i;
    float dtv = dt2[grow * DIN + d0 + jj];
    sdt[i][jj] = dtv;
    sdx[i][jj] = dtv * xc[(rloc0 + i) * DIN + d0 + jj];
    sB[i][jj]  = dbc2[grow * 37 + 5 + jj];
    sC[i][jj]  = dbc2[grow * 37 + 21 + jj];
  }
  __syncthreads();
  for (int i = 0; i < LCH; ++i) {
    float a = __expf(sdt[i][dl] * Areg);
    h = a * h + sdx[i][dl] * sB[i][n];
    float y = h * sC[i][n];
    y += __shfl_xor(y, 1);
    y += __shfl_xor(y, 2);
    y += __shfl_xor(y, 4);
    y += __shfl_xor(y, 8);
    if (n == 0) sY[i][dl] = y;
  }
  __syncthreads();
  for (int e = tid; e < LCH * 16; e += 256) {
    int i = e >> 4, jj = e & 15;
    int t = cch * LCH + i;
    int rloc = b * T_ + t;
    float xcv = xc[rloc * DIN + d0 + jj];
    int orow = dir ? (b * T_ + (T_ - 1 - t)) : rloc;
    float z = xz[orow * 320 + 160 + d0 + jj];
    float sg = 1.f / (1.f + __expf(-z));
    ygcat[orow * 320 + dir * 160 + d0 + jj] = (sY[i][jj] + xcv * Dp[d0 + jj]) * (z * sg);
  }
}

// ---- pooling: per-(b,c) mean/std over T -------------------------------------
__global__ __launch_bounds__(256) void stats_k(const float* __restrict__ x,
                                               float* __restrict__ meanv, float* __restrict__ stdv) {
  int bc = blockIdx.x; int b = bc / C_, c = bc % C_;
  __shared__ float sb[4];
  int tid = threadIdx.x;
  float v[4]; float s = 0.f;
  #pragma unroll
  for (int i = 0; i < 4; ++i) {
    int t = tid + i * 256;
    v[i] = (t < T_) ? x[(b * T_ + t) * C_ + c] : 0.f;
    s += v[i];
  }
  s = blockSum(s, sb);
  float mu = s * (1.f / T_);
  float q = 0.f;
  #pragma unroll
  for (int i = 0; i < 4; ++i) {
    int t = tid + i * 256;
    if (t < T_) { float dd = v[i] - mu; q += dd * dd; }
  }
  q = blockSum(q, sb);
  if (tid == 0) { meanv[bc] = mu; stdv[bc] = sqrtf(fmaxf(q * (1.f / T_), 1e-12f)); }
}

// ---- att1 pack --------------------------------------------------------------
__global__ __launch_bounds__(256) void prep_k(const float* __restrict__ meanv,
    const float* __restrict__ stdv, fp w1, fp ab1, fp g1p, fp b1p, fp m1p, fp v1p,
    float* __restrict__ pack) {
  int idx = blockIdx.x * 256 + threadIdx.x;
  if (idx < 512) {
    int b = idx / 128, dcol = idx % 128;
    float acc = ab1[dcol];
    for (int c = 0; c < C_; ++c) {
      acc += meanv[b * C_ + c] * w1[(C_ + c) * 128 + dcol];
      acc += stdv[b * C_ + c] * w1[(2 * C_ + c) * 128 + dcol];
    }
    pack[idx] = acc;
  } else if (idx < 640) {
    int dcol = idx - 512;
    float kv = g1p[dcol] * rsqrtf(v1p[dcol] + 1e-5f);
    pack[512 + dcol] = kv;
    pack[640 + dcol] = b1p[dcol] - m1p[dcol] * kv;
  }
}

// ---- softmax over T + weighted stats + bn2 ----------------------------------
__global__ __launch_bounds__(256) void pool_k(const float* __restrict__ x,
    const float* __restrict__ scores, fp g2, fp b2, fp m2, fp v2,
    float* __restrict__ pooledn) {
  int bc = blockIdx.x; int b = bc / C_, c = bc % C_;
  __shared__ float sb[4];
  int tid = threadIdx.x;
  float sv[4], xv[4];
  float mx = -1e30f;
  #pragma unroll
  for (int i = 0; i < 4; ++i) {
    int t = tid + i * 256;
    if (t < T_) { sv[i] = scores[(b * T_ + t) * C_ + c]; xv[i] = x[(b * T_ + t) * C_ + c]; }
    else { sv[i] = -1e30f; xv[i] = 0.f; }
    mx = fmaxf(mx, sv[i]);
  }
  mx = blockMax(mx, sb);
  float se = 0.f, sx = 0.f, sxx = 0.f;
  #pragma unroll
  for (int i = 0; i < 4; ++i) {
    float e = expf(sv[i] - mx);
    se += e; sx += e * xv[i]; sxx += e * xv[i] * xv[i];
  }
  se = blockSum(se, sb);
  sx = blockSum(sx, sb);
  sxx = blockSum(sxx, sb);
  if (tid == 0) {
    float mu = sx / se;
    float sg = sqrtf(fmaxf(sxx / se - mu * mu, 1e-12f));
    int j0 = c, j1 = C_ + c;
    pooledn[b * 160 + j0] = (mu - m2[j0]) * rsqrtf(v2[j0] + 1e-5f) * g2[j0] + b2[j0];
    pooledn[b * 160 + j1] = (sg - m2[j1]) * rsqrtf(v2[j1] + 1e-5f) * g2[j1] + b2[j1];
  }
}

// ---- final fc ---------------------------------------------------------------
__global__ __launch_bounds__(256) void fc_k(const float* __restrict__ pooledn, fp fw, fp fb,
                                            float* __restrict__ out) {
  int idx = blockIdx.x * 256 + threadIdx.x;
  if (idx >= 4 * 192) return;
  int b = idx / 192, e = idx % 192;
  float acc = fb[e];
  for (int i = 0; i < 160; ++i) acc += pooledn[b * 160 + i] * fw[i * 192 + e];
  out[idx] = acc;
}

extern "C" void kernel_launch(void* const* d_in, const int* in_sizes, int n_in,
                              void* d_out, int out_size, void* d_ws, size_t ws_size,
                              hipStream_t stream) {
  fp feat   = (fp)d_in[0];
  fp ln1_g  = (fp)d_in[1];  fp ln1_b  = (fp)d_in[2];
  fp in_proj= (fp)d_in[3];
  fp conv_w = (fp)d_in[4];  fp conv_b = (fp)d_in[5];
  fp x_proj = (fp)d_in[6];
  fp dt_w   = (fp)d_in[7];  fp dt_b   = (fp)d_in[8];
  fp A_log  = (fp)d_in[9];  fp Dp     = (fp)d_in[10];
  fp out_proj=(fp)d_in[11];
  fp ln2_g  = (fp)d_in[12]; fp ln2_b  = (fp)d_in[13];
  fp ff_w1  = (fp)d_in[14]; fp ff_b1  = (fp)d_in[15];
  fp ff_w2  = (fp)d_in[16]; fp ff_b2  = (fp)d_in[17];
  fp att_w1 = (fp)d_in[18]; fp att_b1 = (fp)d_in[19];
  fp bn1_g  = (fp)d_in[20]; fp bn1_b  = (fp)d_in[21];
  fp bn1_m  = (fp)d_in[22]; fp bn1_v  = (fp)d_in[23];
  fp att_w2 = (fp)d_in[24]; fp att_b2 = (fp)d_in[25];
  fp bn2_g  = (fp)d_in[26]; fp bn2_b  = (fp)d_in[27];
  fp bn2_m  = (fp)d_in[28]; fp bn2_v  = (fp)d_in[29];
  fp fc_w   = (fp)d_in[30]; fp fc_b   = (fp)d_in[31];

  float* ws   = (float*)d_ws;
  float* x    = ws;               // 256000
  float* xz   = ws + 256000;      // 1024000
  float* xcf  = ws + 1280000;     // 512000
  float* xcb  = ws + 1792000;     // 512000
  float* dbc2 = ws + 2304000;     // 236800
  float* dt2  = ws + 2540800;     // 1024000
  float* hend = ws + 3564800;     // 327680
  float* pprod= ws + 3892480;     // 327680
  float* ygcat= ws + 4220160;     // 1024000
  float* sbuf = ws + 5244160;     // 256000
  float* meanv= ws + 5500160;     // 320
  float* stdv = ws + 5500480;     // 320
  float* pack = ws + 5500800;     // 768
  float* pooledn = ws + 5501568;  // 640
  float* wp   = ws + 5502208;     // 614400 (12*2*25600)
  float* uvb  = ws + 6116608;     // 15360  (12*2*640)
  float* mst_x= ws + 6131968;     // 6400
  float* mst_s= ws + 6138368;     // 6400
  float* xpt  = ws + 6144768;     // 71040 (end 6215808 = 24.9 MiB)
  float* g1   = xz;               // alias: xz free after scanC
  float* a1b  = hend;             // alias: pooling only
  float* sc   = dt2;              // alias: pooling only

  prepw_k<<<30, 256, 0, stream>>>(in_proj, ff_w1, ln1_g, ln1_b, ln2_g, ln2_b,
                                  ff_b1, wp, uvb);
  prepx_k<<<278, 256, 0, stream>>>(x_proj, xpt);
  cmn_k<<<320, 256, 0, stream>>>(feat, x);
  rstat_k<<<200, 256, 0, stream>>>(x, mst_x);

  for (int l = 0; l < 12; ++l) {
    gw_k<0><<<250, 256, 0, stream>>>(x, wp + (2 * l) * 25600, uvb + (2 * l) * 640,
                                     mst_x, nullptr, xz, 320);
    cxf_k<<<400, 256, 0, stream>>>(xz, conv_w + l * 640, conv_b + l * 160,
                                   xpt + l * 5920, dt_w + l * 800, dt_b + l * 160,
                                   xcf, xcb, dbc2, dt2);
    scanA_k<<<1280, 256, 0, stream>>>(dt2, xcf, xcb, dbc2, A_log + l * 2560, hend, pprod);
    scanC_k<<<1280, 256, 0, stream>>>(dt2, dbc2, xcf, xcb, xz, A_log + l * 2560,
                                      Dp + l * 160, hend, pprod, ygcat);
    gc_k<0, 160, 1, 1, 1><<<200, 256, 0, stream>>>(ygcat, out_proj + l * 12800,
                                                   nullptr, nullptr, sbuf, 320, mst_s);
    gw_k<1><<<250, 256, 0, stream>>>(sbuf, wp + (2 * l + 1) * 25600,
                                     uvb + (2 * l + 1) * 640, mst_s, nullptr, g1, 320);
    gc_k<2, 160, 2, 0, 1><<<200, 256, 0, stream>>>(g1, ff_w2 + l * 25600,
                                                   ff_b2 + l * 80, x, x, 320, mst_x);
  }

  stats_k<<<320, 256, 0, stream>>>(x, meanv, stdv);
  prep_k<<<3, 256, 0, stream>>>(meanv, stdv, att_w1, att_b1, bn1_g, bn1_b, bn1_m, bn1_v, pack);
  gw_k<3><<<100, 256, 0, stream>>>(x, att_w1, nullptr, nullptr, pack, a1b, 128);
  gc_k<4, 128, 1, 0, 0><<<200, 256, 0, stream>>>(a1b, att_w2, att_b2, nullptr, sc, 128, nullptr);
  pool_k<<<320, 256, 0, stream>>>(x, sc, bn2_g, bn2_b, bn2_m, bn2_v, pooledn);
  fc_k<<<3, 256, 0, stream>>>(pooledn, fc_w, fc_b, (float*)d_out);
}

// Round 10
// 1261.597 us; speedup vs baseline: 1.1320x; 1.0913x over previous
//
#include <hip/hip_runtime.h>
#include <hip/hip_bf16.h>

#define B_ 4
#define C_ 80
#define T_ 800
#define R_ 3200   // B_*T_
#define DIN 160
#define NST 16
#define NC 16     // time chunks for parallel scan
#define LCH 50    // T_/NC

typedef const float* fp;

__device__ __forceinline__ void g2l16(const float* g, float* l) {
  __builtin_amdgcn_global_load_lds(
      (const __attribute__((address_space(1))) void*)g,
      (__attribute__((address_space(3))) void*)l,
      16, 0, 0);
}

__device__ __forceinline__ float blockSum(float v, float* sb) {
  for (int o = 32; o; o >>= 1) v += __shfl_xor(v, o);
  __syncthreads();
  if ((threadIdx.x & 63) == 0) sb[threadIdx.x >> 6] = v;
  __syncthreads();
  return sb[0] + sb[1] + sb[2] + sb[3];
}
__device__ __forceinline__ float blockMax(float v, float* sb) {
  for (int o = 32; o; o >>= 1) v = fmaxf(v, __shfl_xor(v, o));
  __syncthreads();
  if ((threadIdx.x & 63) == 0) sb[threadIdx.x >> 6] = v;
  __syncthreads();
  return fmaxf(fmaxf(sb[0], sb[1]), fmaxf(sb[2], sb[3]));
}

// ---- prep: W' = diag(g)W, u = colsum(W'), v = b@W (+bias), all 12 layers ----
__global__ __launch_bounds__(256) void prepw_k(fp in_proj, fp ff_w1,
    fp ln1_g, fp ln1_b, fp ln2_g, fp ln2_b, fp ff_b1,
    float* __restrict__ wp, float* __restrict__ uvb) {
  int idx = blockIdx.x * 256 + threadIdx.x;   // 0..7679
  int c = idx % 320, lm = idx / 320;
  int mat = lm & 1, l = lm >> 1;
  fp W = (mat ? ff_w1 : in_proj) + l * 25600;
  fp g = (mat ? ln2_g : ln1_g) + l * 80;
  fp b = (mat ? ln2_b : ln1_b) + l * 80;
  float* wpo = wp + lm * 25600;
  float u = 0.f, v = 0.f;
  for (int k = 0; k < 80; ++k) {
    float w = W[k * 320 + c];
    float gw = g[k] * w;
    wpo[k * 320 + c] = gw;
    u += gw;
    v += b[k] * w;
  }
  if (mat) v += ff_b1[l * 320 + c];
  uvb[lm * 640 + c] = u;
  uvb[lm * 640 + 320 + c] = v;
}

// ---- prep: transpose x_proj -> xpt[l][37][160] ------------------------------
__global__ __launch_bounds__(256) void prepx_k(fp x_proj, float* __restrict__ xpt) {
  int idx = blockIdx.x * 256 + threadIdx.x;   // 12*5920 = 71040
  if (idx >= 71040) return;
  int l = idx / 5920, r = idx % 5920;
  int c = r / 160, k = r % 160;
  xpt[idx] = x_proj[l * 5920 + k * 37 + c];
}

// ---- prep: transpose out_proj -> wot[l][80][160], ff_w2 -> w2t[l][80][320] --
__global__ __launch_bounds__(256) void prept_k(fp out_proj, fp ff_w2,
    float* __restrict__ wot, float* __restrict__ w2t) {
  int idx = blockIdx.x * 256 + threadIdx.x;
  if (idx < 153600) {               // 12 * 80*160
    int l = idx / 12800, r = idx % 12800;
    int c = r / 160, k = r % 160;
    wot[idx] = out_proj[l * 12800 + k * 80 + c];
  } else if (idx < 153600 + 307200) {  // 12 * 80*320
    int j = idx - 153600;
    int l = j / 25600, r = j % 25600;
    int c = r / 320, k = r % 320;
    w2t[j] = ff_w2[l * 25600 + k * 80 + c];
  }
}

// ---- CMN + transpose: feat [B,C,T] -> x [B*T, C] ----------------------------
__global__ __launch_bounds__(256) void cmn_k(fp feat, float* __restrict__ x) {
  int bc = blockIdx.x;
  int b = bc / C_, c = bc % C_;
  const float* f = feat + (b * C_ + c) * T_;
  __shared__ float sb[4];
  int tid = threadIdx.x;
  float v[4]; float s = 0.f;
  #pragma unroll
  for (int i = 0; i < 4; ++i) {
    int t = tid + i * 256;
    v[i] = (t < T_) ? f[t] : 0.f;
    s += v[i];
  }
  s = blockSum(s, sb);
  float mu = s * (1.f / T_);
  #pragma unroll
  for (int i = 0; i < 4; ++i) {
    int t = tid + i * 256;
    if (t < T_) x[(b * T_ + t) * C_ + c] = v[i] - mu;
  }
}

// ---- row stats (mu, rs) for LN fold (layer-0 entry only) --------------------
__global__ __launch_bounds__(256) void rstat_k(const float* __restrict__ in,
                                               float* __restrict__ must) {
  int row = blockIdx.x * 16 + (threadIdx.x >> 4);
  int c16 = threadIdx.x & 15;
  float s = 0.f, q = 0.f;
  #pragma unroll
  for (int m = 0; m < 5; ++m) {
    float v = in[row * 80 + c16 + 16 * m];
    s += v; q += v * v;
  }
  s += __shfl_xor(s, 1); s += __shfl_xor(s, 2);
  s += __shfl_xor(s, 4); s += __shfl_xor(s, 8);
  q += __shfl_xor(q, 1); q += __shfl_xor(q, 2);
  q += __shfl_xor(q, 4); q += __shfl_xor(q, 8);
  if (c16 == 0) {
    float mu = s * 0.0125f;
    float rs = rsqrtf(fmaxf(q * 0.0125f - mu * mu, 0.f) + 1e-5f);
    must[row * 2] = mu;
    must[row * 2 + 1] = rs;
  }
}

// ---- per-wave GEMM, K=80, TN=64; LN folded via uv/must ----------------------
// EPI: 0 plain+LNfold, 3 att1 (pack in extra, no LN)
template<int EPI>
__global__ __launch_bounds__(256, 4) void gw_k(const float* __restrict__ A,
    fp W, fp uv, const float* __restrict__ must, const float* __restrict__ extra,
    float* __restrict__ out, int N) {
  __shared__ float SL[5120 + 4 * 1280];
  int tid = threadIdx.x, wv = tid >> 6, ln = tid & 63;
  int bid = blockIdx.x;
  int c0 = (bid / 50) * 64;
  int row0 = ((bid % 50) * 4 + wv) * 16;
  for (int ch = wv; ch < 20; ch += 4) {
    int m = ch * 256 + ln * 4;
    int kr = m >> 6, cc = m & 63;
    int lo = __builtin_amdgcn_readfirstlane(ch * 256);
    g2l16(W + kr * N + c0 + cc, SL + lo);
  }
  int abase = __builtin_amdgcn_readfirstlane(5120 + wv * 1280);
  float* As = SL + 5120 + wv * 1280;
  #pragma unroll
  for (int i = 0; i < 5; ++i) {
    int m = i * 256 + ln * 4;
    int r = m / 80, kk = m - r * 80;
    g2l16(A + (row0 + r) * 80 + kk, SL + abase + i * 256);
  }
  __syncthreads();
  int rq = ln >> 4, c16 = ln & 15;
  float acc[4][4] = {};
  #pragma unroll 2
  for (int k4 = 0; k4 < 80; k4 += 4) {
    float4 a[4], w[4];
    #pragma unroll
    for (int i = 0; i < 4; ++i)
      a[i] = *(const float4*)&As[(rq * 4 + i) * 80 + k4];
    #pragma unroll
    for (int kk = 0; kk < 4; ++kk)
      w[kk] = *(const float4*)&SL[(k4 + kk) * 64 + c16 * 4];
    #pragma unroll
    for (int i = 0; i < 4; ++i) {
      acc[i][0] += a[i].x*w[0].x + a[i].y*w[1].x + a[i].z*w[2].x + a[i].w*w[3].x;
      acc[i][1] += a[i].x*w[0].y + a[i].y*w[1].y + a[i].z*w[2].y + a[i].w*w[3].y;
      acc[i][2] += a[i].x*w[0].z + a[i].y*w[1].z + a[i].z*w[2].z + a[i].w*w[3].z;
      acc[i][3] += a[i].x*w[0].w + a[i].y*w[1].w + a[i].z*w[2].w + a[i].w*w[3].w;
    }
  }
  float ua[4], va[4];
  if (EPI != 3) {
    *(float4*)ua = *(const float4*)&uv[c0 + c16 * 4];
    *(float4*)va = *(const float4*)&uv[N + c0 + c16 * 4];
  }
  #pragma unroll
  for (int i = 0; i < 4; ++i) {
    int row = row0 + rq * 4 + i;
    float mu = 0.f, rs = 1.f;
    if (EPI != 3) {
      float2 ms = *(const float2*)&must[row * 2];
      mu = ms.x; rs = ms.y;
    }
    float4 o;
    float* op = &o.x;
    #pragma unroll
    for (int j = 0; j < 4; ++j) {
      float v = acc[i][j];
      if (EPI == 3) {
        int c = c0 + c16 * 4 + j;
        v += extra[(row / T_) * 128 + c];
        v = fmaxf(v, 0.f);
        v = v * extra[512 + c] + extra[640 + c];
        v = tanhf(v);
      } else {
        v = rs * v - mu * rs * ua[j] + va[j];
      }
      op[j] = v;
    }
    *(float4*)&out[row * N + c0 + c16 * 4] = o;
  }
}

// ---- block-coop GEMM (pooling att2 only) ------------------------------------
template<int EPI, int KCH, int NKC, int SUM2, int STAT>
__global__ __launch_bounds__(256, 4) void gc_k(const float* __restrict__ A,
    fp W, fp bias, const float* __restrict__ extra, float* __restrict__ out,
    int Astride, float* __restrict__ must) {
  constexpr int P = KCH + 4;
  __shared__ float As[16 * P];
  __shared__ float Wt[80 * P];
  int tid = threadIdx.x;
  int row0 = blockIdx.x * 16;
  int rr = tid >> 4, c16 = tid & 15;
  float acc[5] = {};
  for (int kc = 0; kc < NKC; ++kc) {
    if (kc) __syncthreads();
    #pragma unroll
    for (int i = 0; i < 16 * KCH / 256; ++i) {
      int e = tid + i * 256;
      int r = e / KCH, k = e - r * KCH;
      float v;
      if (SUM2) v = A[(row0 + r) * 320 + k] + A[(row0 + r) * 320 + 160 + k];
      else      v = A[(row0 + r) * Astride + kc * KCH + k];
      As[r * P + k] = v;
    }
    #pragma unroll
    for (int i = 0; i < KCH * 80 / 256; ++i) {
      int e = tid + i * 256;
      int kr = e / 80, c = e - kr * 80;
      Wt[c * P + kr] = W[(kc * KCH + kr) * 80 + c];
    }
    __syncthreads();
    #pragma unroll 4
    for (int k4 = 0; k4 < KCH; k4 += 4) {
      float4 a = *(const float4*)&As[rr * P + k4];
      #pragma unroll
      for (int m = 0; m < 5; ++m) {
        float4 w = *(const float4*)&Wt[(c16 + 16 * m) * P + k4];
        acc[m] += a.x * w.x + a.y * w.y + a.z * w.z + a.w * w.w;
      }
    }
  }
  int row = row0 + rr;
  #pragma unroll
  for (int m = 0; m < 5; ++m) {
    int c = c16 + 16 * m;
    float v = acc[m];
    if (EPI == 2) v += bias[c] + extra[row * 80 + c];
    else if (EPI == 4) v += bias[c];
    out[row * 80 + c] = v;
  }
}

// ---- gof: out_proj(sum fwd/bwd) + in-block LN2 + ff1 + GELU -----------------
// grid 200 x 256; one 16-row block; sbuf never leaves LDS
__global__ __launch_bounds__(256, 2) void gof_k(const float* __restrict__ yg,
    fp wotl, fp w1pl, fp uv1, float* __restrict__ g1) {
  __shared__ float As[16 * 164];
  __shared__ float Wt[80 * 164];
  __shared__ float sl[16 * 84];
  __shared__ float ss[32];
  int tid = threadIdx.x, row0 = blockIdx.x * 16, rr = tid >> 4, c16 = tid & 15;
  #pragma unroll
  for (int i = 0; i < 10; ++i) {
    int e = tid + i * 256; int r = e / 160, k = e - r * 160;
    As[r * 164 + k] = yg[(row0 + r) * 320 + k] + yg[(row0 + r) * 320 + 160 + k];
  }
  #pragma unroll
  for (int i = 0; i < 50; ++i) {
    int e = tid + i * 256; int c = e / 160, k = e - c * 160;
    Wt[c * 164 + k] = wotl[e];
  }
  __syncthreads();
  float acc[5] = {};
  #pragma unroll 4
  for (int k4 = 0; k4 < 160; k4 += 4) {
    float4 a = *(const float4*)&As[rr * 164 + k4];
    #pragma unroll
    for (int m = 0; m < 5; ++m) {
      float4 w = *(const float4*)&Wt[(c16 + 16 * m) * 164 + k4];
      acc[m] += a.x * w.x + a.y * w.y + a.z * w.z + a.w * w.w;
    }
  }
  float s = 0.f, q = 0.f;
  #pragma unroll
  for (int m = 0; m < 5; ++m) {
    float v = acc[m];
    sl[rr * 84 + c16 + 16 * m] = v;
    s += v; q += v * v;
  }
  s += __shfl_xor(s, 1); s += __shfl_xor(s, 2);
  s += __shfl_xor(s, 4); s += __shfl_xor(s, 8);
  q += __shfl_xor(q, 1); q += __shfl_xor(q, 2);
  q += __shfl_xor(q, 4); q += __shfl_xor(q, 8);
  if (c16 == 0) {
    float mu = s * 0.0125f;
    ss[rr * 2] = mu;
    ss[rr * 2 + 1] = rsqrtf(fmaxf(q * 0.0125f - mu * mu, 0.f) + 1e-5f);
  }
  for (int h = 0; h < 2; ++h) {
    __syncthreads();
    #pragma unroll
    for (int i = 0; i < 50; ++i) {
      int e = tid + i * 256; int kr = e / 160, c = e - kr * 160;
      Wt[kr * 164 + c] = w1pl[kr * 320 + h * 160 + c];
    }
    __syncthreads();
    float mu = ss[rr * 2], rs = ss[rr * 2 + 1];
    float a2[10] = {};
    for (int k = 0; k < 80; k += 4) {
      float4 av = *(const float4*)&sl[rr * 84 + k];
      #pragma unroll
      for (int m = 0; m < 10; ++m) {
        int c = c16 + 16 * m;
        a2[m] += av.x * Wt[k * 164 + c] + av.y * Wt[(k + 1) * 164 + c]
               + av.z * Wt[(k + 2) * 164 + c] + av.w * Wt[(k + 3) * 164 + c];
      }
    }
    #pragma unroll
    for (int m = 0; m < 10; ++m) {
      int c = h * 160 + c16 + 16 * m;
      float v = rs * a2[m] - mu * rs * uv1[c] + uv1[320 + c];
      v = 0.5f * v * (1.f + erff(v * 0.70710678118f));
      g1[(row0 + rr) * 320 + c] = v;
    }
  }
}

// ---- gfi: ff2 + bias + residual + in-block LN1 + next-layer in_proj ---------
template<int LAST>
__global__ __launch_bounds__(256, 2) void gfi_k(const float* __restrict__ g1,
    fp w2tl, fp fb2, float* __restrict__ x, fp wpn, fp uvn,
    float* __restrict__ xz) {
  __shared__ float As[16 * 164];
  __shared__ float Wt[80 * 164];
  __shared__ float xn[16 * 84];
  __shared__ float ss[32];
  int tid = threadIdx.x, row0 = blockIdx.x * 16, rr = tid >> 4, c16 = tid & 15;
  float acc[5] = {};
  for (int kc = 0; kc < 2; ++kc) {
    if (kc) __syncthreads();
    #pragma unroll
    for (int i = 0; i < 10; ++i) {
      int e = tid + i * 256; int r = e / 160, k = e - r * 160;
      As[r * 164 + k] = g1[(row0 + r) * 320 + kc * 160 + k];
    }
    #pragma unroll
    for (int i = 0; i < 50; ++i) {
      int e = tid + i * 256; int c = e / 160, k = e - c * 160;
      Wt[c * 164 + k] = w2tl[c * 320 + kc * 160 + k];
    }
    __syncthreads();
    #pragma unroll 4
    for (int k4 = 0; k4 < 160; k4 += 4) {
      float4 a = *(const float4*)&As[rr * 164 + k4];
      #pragma unroll
      for (int m = 0; m < 5; ++m) {
        float4 w = *(const float4*)&Wt[(c16 + 16 * m) * 164 + k4];
        acc[m] += a.x * w.x + a.y * w.y + a.z * w.z + a.w * w.w;
      }
    }
  }
  float s = 0.f, q = 0.f;
  #pragma unroll
  for (int m = 0; m < 5; ++m) {
    int c = c16 + 16 * m;
    float v = acc[m] + fb2[c] + x[(row0 + rr) * 80 + c];
    x[(row0 + rr) * 80 + c] = v;
    xn[rr * 84 + c] = v;
    s += v; q += v * v;
  }
  if (!LAST) {
    s += __shfl_xor(s, 1); s += __shfl_xor(s, 2);
    s += __shfl_xor(s, 4); s += __shfl_xor(s, 8);
    q += __shfl_xor(q, 1); q += __shfl_xor(q, 2);
    q += __shfl_xor(q, 4); q += __shfl_xor(q, 8);
    if (c16 == 0) {
      float mu = s * 0.0125f;
      ss[rr * 2] = mu;
      ss[rr * 2 + 1] = rsqrtf(fmaxf(q * 0.0125f - mu * mu, 0.f) + 1e-5f);
    }
    for (int h = 0; h < 2; ++h) {
      __syncthreads();
      #pragma unroll
      for (int i = 0; i < 50; ++i) {
        int e = tid + i * 256; int kr = e / 160, c = e - kr * 160;
        Wt[kr * 164 + c] = wpn[kr * 320 + h * 160 + c];
      }
      __syncthreads();
      float mu = ss[rr * 2], rs = ss[rr * 2 + 1];
      float a2[10] = {};
      for (int k = 0; k < 80; k += 4) {
        float4 av = *(const float4*)&xn[rr * 84 + k];
        #pragma unroll
        for (int m = 0; m < 10; ++m) {
          int c = c16 + 16 * m;
          a2[m] += av.x * Wt[k * 164 + c] + av.y * Wt[(k + 1) * 164 + c]
                 + av.z * Wt[(k + 2) * 164 + c] + av.w * Wt[(k + 3) * 164 + c];
        }
      }
      #pragma unroll
      for (int m = 0; m < 10; ++m) {
        int c = h * 160 + c16 + 16 * m;
        xz[(row0 + rr) * 320 + c] = rs * a2[m] - mu * rs * uvn[c] + uvn[320 + c];
      }
    }
  }
}

// ---- fused conv+SiLU + x_proj + dt_proj+softplus (xpt staged in padded LDS) -
__global__ __launch_bounds__(256) void cxf_k(const float* __restrict__ xz,
    fp cw, fp cb, fp xptl, fp dtw, fp dtb,
    float* __restrict__ xcf, float* __restrict__ xcbb,
    float* __restrict__ dbc2, float* __restrict__ dt2) {
  __shared__ float As[16 * 164];
  __shared__ float xpT[37 * 164];
  __shared__ float dbcl[16 * 40];
  int bi = blockIdx.x;
  int tc = bi % 50; int rem = bi / 50;
  int b = rem & 3, dir = rem >> 2;
  int t0 = tc * 16;
  int tid = threadIdx.x;
  // stage pre-transposed x_proj into padded LDS (stride-1 writes)
  #pragma unroll
  for (int i = 0; i < 24; ++i) {
    int e = tid + i * 256;
    if (e < 5920) {
      int c = e / 160, k = e - c * 160;
      xpT[c * 164 + k] = xptl[e];
    }
  }
  float* xco = dir ? xcbb : xcf;
  #pragma unroll
  for (int i = 0; i < 3; ++i) {
    int e = tid + i * 256;
    if (e < 640) {
      int ii = e / 40, d4 = (e - ii * 40) * 4;
      int t = t0 + ii;
      float4 acc = *(const float4*)&cb[d4];
      #pragma unroll
      for (int k = 0; k < 4; ++k) {
        int tt = t - 3 + k;
        if (tt >= 0) {
          int src = dir ? (T_ - 1 - tt) : tt;
          float4 xv = *(const float4*)&xz[(b * T_ + src) * 320 + d4];
          float4 wv = *(const float4*)&cw[k * DIN + d4];
          acc.x += wv.x * xv.x; acc.y += wv.y * xv.y;
          acc.z += wv.z * xv.z; acc.w += wv.w * xv.w;
        }
      }
      float4 o;
      o.x = acc.x / (1.f + __expf(-acc.x));
      o.y = acc.y / (1.f + __expf(-acc.y));
      o.z = acc.z / (1.f + __expf(-acc.z));
      o.w = acc.w / (1.f + __expf(-acc.w));
      *(float4*)&As[ii * 164 + d4] = o;
      *(float4*)&xco[(b * T_ + t) * DIN + d4] = o;
    }
  }
  __syncthreads();
  int rr = tid >> 4, c16 = tid & 15;
  int grow0 = dir * R_ + b * T_ + t0;
  {
    float a0 = 0.f, a1 = 0.f, a2 = 0.f;
    for (int k4 = 0; k4 < 160; k4 += 4) {
      float4 a = *(const float4*)&As[rr * 164 + k4];
      float4 w0 = *(const float4*)&xpT[c16 * 164 + k4];
      float4 w1 = *(const float4*)&xpT[(c16 + 16) * 164 + k4];
      a0 += a.x * w0.x + a.y * w0.y + a.z * w0.z + a.w * w0.w;
      a1 += a.x * w1.x + a.y * w1.y + a.z * w1.z + a.w * w1.w;
      if (c16 < 5) {
        float4 w2 = *(const float4*)&xpT[(c16 + 32) * 164 + k4];
        a2 += a.x * w2.x + a.y * w2.y + a.z * w2.z + a.w * w2.w;
      }
    }
    dbcl[rr * 40 + c16] = a0;
    dbcl[rr * 40 + c16 + 16] = a1;
    dbc2[(grow0 + rr) * 37 + c16] = a0;
    dbc2[(grow0 + rr) * 37 + c16 + 16] = a1;
    if (c16 < 5) {
      dbcl[rr * 40 + c16 + 32] = a2;
      dbc2[(grow0 + rr) * 37 + c16 + 32] = a2;
    }
  }
  __syncthreads();
  #pragma unroll
  for (int i = 0; i < 10; ++i) {
    int e = tid + i * 256;
    int ii = e / 160, d = e - ii * 160;
    float v = dtb[d];
    #pragma unroll
    for (int m = 0; m < 5; ++m) v += dbcl[ii * 40 + m] * dtw[m * DIN + d];
    v = fmaxf(v, 0.f) + __logf(1.f + __expf(-fabsf(v)));
    dt2[(grow0 + ii) * DIN + d] = v;
  }
}

// ---- chunked parallel scan, phase A -----------------------------------------
__global__ __launch_bounds__(256) void scanA_k(const float* __restrict__ dt2,
    const float* __restrict__ xcf, const float* __restrict__ xcbb,
    const float* __restrict__ dbc2, fp A_log,
    float* __restrict__ hend, float* __restrict__ pprod) {
  int bi = blockIdx.x;
  int cch = bi % NC; int rem = bi / NC;
  int dblk = rem % 10; rem /= 10;
  int b = rem % 4; int dir = rem / 4;
  int d0 = dblk * 16;
  int tid = threadIdx.x, dl = tid >> 4, n = tid & 15;
  int d = d0 + dl;
  float Areg = -__expf(A_log[d * NST + n]);
  __shared__ float sdt[LCH][16], sdx[LCH][16], sB[LCH][16];
  const float* xc = dir ? xcbb : xcf;
  int rbase = dir * R_ + b * T_ + cch * LCH;
  int rloc0 = b * T_ + cch * LCH;
  for (int e = tid; e < LCH * 16; e += 256) {
    int i = e >> 4, jj = e & 15;
    int grow = rbase + i;
    float dtv = dt2[grow * DIN + d0 + jj];
    sdt[i][jj] = dtv;
    sdx[i][jj] = dtv * xc[(rloc0 + i) * DIN + d0 + jj];
    sB[i][jj]  = dbc2[grow * 37 + 5 + jj];
  }
  __syncthreads();
  float h = 0.f, dts = 0.f;
  #pragma unroll 2
  for (int i = 0; i < LCH; ++i) {
    float dtv = sdt[i][dl];
    float a = __expf(dtv * Areg);
    h = a * h + sdx[i][dl] * sB[i][n];
    dts += dtv;
  }
  hend[bi * 256 + tid] = h;
  pprod[bi * 256 + tid] = __expf(dts * Areg);
}

// ---- phase C: prefix (scanB fused) + recompute chunk + gated write ----------
__global__ __launch_bounds__(256) void scanC_k(const float* __restrict__ dt2,
    const float* __restrict__ dbc2, const float* __restrict__ xcf,
    const float* __restrict__ xcbb, const float* __restrict__ xz,
    fp A_log, fp Dp, const float* __restrict__ hend,
    const float* __restrict__ pprod, float* __restrict__ ygcat) {
  int bi = blockIdx.x;
  int cch = bi % NC; int rem = bi / NC;
  int dblk = rem % 10; rem /= 10;
  int b = rem % 4; int dir = rem / 4;
  int d0 = dblk * 16;
  int tid = threadIdx.x, dl = tid >> 4, n = tid & 15;
  int d = d0 + dl;
  float Areg = -__expf(A_log[d * NST + n]);
  __shared__ float sdt[LCH][16], sdx[LCH][16], sB[LCH][16], sC[LCH][16];
  __shared__ float sY[LCH][16];
  const float* xc = dir ? xcbb : xcf;
  int rbase = dir * R_ + b * T_ + cch * LCH;
  int rloc0 = b * T_ + cch * LCH;
  int sbase = (bi / NC) * (NC * 256) + tid;
  float h = 0.f;
  #pragma unroll
  for (int cc = 0; cc < NC; ++cc) {
    float p = pprod[sbase + cc * 256];
    float e = hend[sbase + cc * 256];
    if (cc < cch) h = p * h + e;
  }
  for (int e = tid; e < LCH * 16; e += 256) {
    int i = e >> 4, jj = e & 15;
    int grow = rbase + i;
    float dtv = dt2[grow * DIN + d0 + jj];
    sdt[i][jj] = dtv;
    sdx[i][jj] = dtv * xc[(rloc0 + i) * DIN + d0 + jj];
    sB[i][jj]  = dbc2[grow * 37 + 5 + jj];
    sC[i][jj]  = dbc2[grow * 37 + 21 + jj];
  }
  __syncthreads();
  for (int i = 0; i < LCH; ++i) {
    float a = __expf(sdt[i][dl] * Areg);
    h = a * h + sdx[i][dl] * sB[i][n];
    float y = h * sC[i][n];
    y += __shfl_xor(y, 1);
    y += __shfl_xor(y, 2);
    y += __shfl_xor(y, 4);
    y += __shfl_xor(y, 8);
    if (n == 0) sY[i][dl] = y;
  }
  __syncthreads();
  for (int e = tid; e < LCH * 16; e += 256) {
    int i = e >> 4, jj = e & 15;
    int t = cch * LCH + i;
    int rloc = b * T_ + t;
    float xcv = xc[rloc * DIN + d0 + jj];
    int orow = dir ? (b * T_ + (T_ - 1 - t)) : rloc;
    float z = xz[orow * 320 + 160 + d0 + jj];
    float sg = 1.f / (1.f + __expf(-z));
    ygcat[orow * 320 + dir * 160 + d0 + jj] = (sY[i][jj] + xcv * Dp[d0 + jj]) * (z * sg);
  }
}

// ---- pooling: per-(b,c) mean/std over T -------------------------------------
__global__ __launch_bounds__(256) void stats_k(const float* __restrict__ x,
                                               float* __restrict__ meanv, float* __restrict__ stdv) {
  int bc = blockIdx.x; int b = bc / C_, c = bc % C_;
  __shared__ float sb[4];
  int tid = threadIdx.x;
  float v[4]; float s = 0.f;
  #pragma unroll
  for (int i = 0; i < 4; ++i) {
    int t = tid + i * 256;
    v[i] = (t < T_) ? x[(b * T_ + t) * C_ + c] : 0.f;
    s += v[i];
  }
  s = blockSum(s, sb);
  float mu = s * (1.f / T_);
  float q = 0.f;
  #pragma unroll
  for (int i = 0; i < 4; ++i) {
    int t = tid + i * 256;
    if (t < T_) { float dd = v[i] - mu; q += dd * dd; }
  }
  q = blockSum(q, sb);
  if (tid == 0) { meanv[bc] = mu; stdv[bc] = sqrtf(fmaxf(q * (1.f / T_), 1e-12f)); }
}

// ---- att1 pack --------------------------------------------------------------
__global__ __launch_bounds__(256) void prep_k(const float* __restrict__ meanv,
    const float* __restrict__ stdv, fp w1, fp ab1, fp g1p, fp b1p, fp m1p, fp v1p,
    float* __restrict__ pack) {
  int idx = blockIdx.x * 256 + threadIdx.x;
  if (idx < 512) {
    int b = idx / 128, dcol = idx % 128;
    float acc = ab1[dcol];
    for (int c = 0; c < C_; ++c) {
      acc += meanv[b * C_ + c] * w1[(C_ + c) * 128 + dcol];
      acc += stdv[b * C_ + c] * w1[(2 * C_ + c) * 128 + dcol];
    }
    pack[idx] = acc;
  } else if (idx < 640) {
    int dcol = idx - 512;
    float kv = g1p[dcol] * rsqrtf(v1p[dcol] + 1e-5f);
    pack[512 + dcol] = kv;
    pack[640 + dcol] = b1p[dcol] - m1p[dcol] * kv;
  }
}

// ---- softmax over T + weighted stats + bn2 ----------------------------------
__global__ __launch_bounds__(256) void pool_k(const float* __restrict__ x,
    const float* __restrict__ scores, fp g2, fp b2, fp m2, fp v2,
    float* __restrict__ pooledn) {
  int bc = blockIdx.x; int b = bc / C_, c = bc % C_;
  __shared__ float sb[4];
  int tid = threadIdx.x;
  float sv[4], xv[4];
  float mx = -1e30f;
  #pragma unroll
  for (int i = 0; i < 4; ++i) {
    int t = tid + i * 256;
    if (t < T_) { sv[i] = scores[(b * T_ + t) * C_ + c]; xv[i] = x[(b * T_ + t) * C_ + c]; }
    else { sv[i] = -1e30f; xv[i] = 0.f; }
    mx = fmaxf(mx, sv[i]);
  }
  mx = blockMax(mx, sb);
  float se = 0.f, sx = 0.f, sxx = 0.f;
  #pragma unroll
  for (int i = 0; i < 4; ++i) {
    float e = expf(sv[i] - mx);
    se += e; sx += e * xv[i]; sxx += e * xv[i] * xv[i];
  }
  se = blockSum(se, sb);
  sx = blockSum(sx, sb);
  sxx = blockSum(sxx, sb);
  if (tid == 0) {
    float mu = sx / se;
    float sg = sqrtf(fmaxf(sxx / se - mu * mu, 1e-12f));
    int j0 = c, j1 = C_ + c;
    pooledn[b * 160 + j0] = (mu - m2[j0]) * rsqrtf(v2[j0] + 1e-5f) * g2[j0] + b2[j0];
    pooledn[b * 160 + j1] = (sg - m2[j1]) * rsqrtf(v2[j1] + 1e-5f) * g2[j1] + b2[j1];
  }
}

// ---- final fc ---------------------------------------------------------------
__global__ __launch_bounds__(256) void fc_k(const float* __restrict__ pooledn, fp fw, fp fb,
                                            float* __restrict__ out) {
  int idx = blockIdx.x * 256 + threadIdx.x;
  if (idx >= 4 * 192) return;
  int b = idx / 192, e = idx % 192;
  float acc = fb[e];
  for (int i = 0; i < 160; ++i) acc += pooledn[b * 160 + i] * fw[i * 192 + e];
  out[idx] = acc;
}

extern "C" void kernel_launch(void* const* d_in, const int* in_sizes, int n_in,
                              void* d_out, int out_size, void* d_ws, size_t ws_size,
                              hipStream_t stream) {
  fp feat   = (fp)d_in[0];
  fp ln1_g  = (fp)d_in[1];  fp ln1_b  = (fp)d_in[2];
  fp in_proj= (fp)d_in[3];
  fp conv_w = (fp)d_in[4];  fp conv_b = (fp)d_in[5];
  fp x_proj = (fp)d_in[6];
  fp dt_w   = (fp)d_in[7];  fp dt_b   = (fp)d_in[8];
  fp A_log  = (fp)d_in[9];  fp Dp     = (fp)d_in[10];
  fp out_proj=(fp)d_in[11];
  fp ln2_g  = (fp)d_in[12]; fp ln2_b  = (fp)d_in[13];
  fp ff_w1  = (fp)d_in[14]; fp ff_b1  = (fp)d_in[15];
  fp ff_w2  = (fp)d_in[16]; fp ff_b2  = (fp)d_in[17];
  fp att_w1 = (fp)d_in[18]; fp att_b1 = (fp)d_in[19];
  fp bn1_g  = (fp)d_in[20]; fp bn1_b  = (fp)d_in[21];
  fp bn1_m  = (fp)d_in[22]; fp bn1_v  = (fp)d_in[23];
  fp att_w2 = (fp)d_in[24]; fp att_b2 = (fp)d_in[25];
  fp bn2_g  = (fp)d_in[26]; fp bn2_b  = (fp)d_in[27];
  fp bn2_m  = (fp)d_in[28]; fp bn2_v  = (fp)d_in[29];
  fp fc_w   = (fp)d_in[30]; fp fc_b   = (fp)d_in[31];

  float* ws   = (float*)d_ws;
  float* x    = ws;               // 256000
  float* xz   = ws + 256000;      // 1024000
  float* xcf  = ws + 1280000;     // 512000
  float* xcb  = ws + 1792000;     // 512000
  float* dbc2 = ws + 2304000;     // 236800
  float* dt2  = ws + 2540800;     // 1024000
  float* hend = ws + 3564800;     // 327680
  float* pprod= ws + 3892480;     // 327680
  float* ygcat= ws + 4220160;     // 1024000
  float* meanv= ws + 5244160;     // 320
  float* stdv = ws + 5244480;     // 320
  float* pack = ws + 5244800;     // 768
  float* pooledn = ws + 5245568;  // 640
  float* wp   = ws + 5246208;     // 614400 (12*2*25600)
  float* uvb  = ws + 5860608;     // 15360
  float* mst_x= ws + 5875968;     // 6400
  float* xpt  = ws + 5882368;     // 71040
  float* wot  = ws + 5953408;     // 153600 (12*80*160)
  float* w2t  = ws + 6107008;     // 307200 (12*80*320)  end 6414208 = 25.7 MiB
  float* g1   = xz;               // alias: xz free after scanC, gof writes, gfi reads own rows then writes xz
  float* a1b  = hend;             // alias: pooling only
  float* sc   = dt2;              // alias: pooling only

  prepw_k<<<30, 256, 0, stream>>>(in_proj, ff_w1, ln1_g, ln1_b, ln2_g, ln2_b,
                                  ff_b1, wp, uvb);
  prepx_k<<<278, 256, 0, stream>>>(x_proj, xpt);
  prept_k<<<1800, 256, 0, stream>>>(out_proj, ff_w2, wot, w2t);
  cmn_k<<<320, 256, 0, stream>>>(feat, x);
  rstat_k<<<200, 256, 0, stream>>>(x, mst_x);
  gw_k<0><<<250, 256, 0, stream>>>(x, wp, uvb, mst_x, nullptr, xz, 320);

  for (int l = 0; l < 12; ++l) {
    cxf_k<<<400, 256, 0, stream>>>(xz, conv_w + l * 640, conv_b + l * 160,
                                   xpt + l * 5920, dt_w + l * 800, dt_b + l * 160,
                                   xcf, xcb, dbc2, dt2);
    scanA_k<<<1280, 256, 0, stream>>>(dt2, xcf, xcb, dbc2, A_log + l * 2560, hend, pprod);
    scanC_k<<<1280, 256, 0, stream>>>(dt2, dbc2, xcf, xcb, xz, A_log + l * 2560,
                                      Dp + l * 160, hend, pprod, ygcat);
    gof_k<<<200, 256, 0, stream>>>(ygcat, wot + l * 12800, wp + (2 * l + 1) * 25600,
                                   uvb + (2 * l + 1) * 640, g1);
    if (l < 11)
      gfi_k<0><<<200, 256, 0, stream>>>(g1, w2t + l * 25600, ff_b2 + l * 80, x,
                                        wp + (2 * l + 2) * 25600,
                                        uvb + (2 * l + 2) * 640, xz);
    else
      gfi_k<1><<<200, 256, 0, stream>>>(g1, w2t + l * 25600, ff_b2 + l * 80, x,
                                        wp, uvb, xz);
  }

  stats_k<<<320, 256, 0, stream>>>(x, meanv, stdv);
  prep_k<<<3, 256, 0, stream>>>(meanv, stdv, att_w1, att_b1, bn1_g, bn1_b, bn1_m, bn1_v, pack);
  gw_k<3><<<100, 256, 0, stream>>>(x, att_w1, nullptr, nullptr, pack, a1b, 128);
  gc_k<4, 128, 1, 0, 0><<<200, 256, 0, stream>>>(a1b, att_w2, att_b2, nullptr, sc, 128, nullptr);
  pool_k<<<320, 256, 0, stream>>>(x, sc, bn2_g, bn2_b, bn2_m, bn2_v, pooledn);
  fc_k<<<3, 256, 0, stream>>>(pooledn, fc_w, fc_b, (float*)d_out);
}